// Round 7
// baseline (322.510 us; speedup 1.0000x reference)
//
#include <hip/hip_runtime.h>
#include <hip/hip_cooperative_groups.h>
#include <stdint.h>

namespace cg = cooperative_groups;

// Problem constants (fixed by reference setup_inputs)
#define N_NODES 8192
#define F_IN    256
#define F_OUT   64
#define N_EDGES 262144
#define LEAKY   0.2f
#define BN_EPSF 1e-5f
#define WPR     256            // bitmap words per row = N_NODES/32
#define MAXDEG  256            // Poisson(32): max row degree ~66; 256 is 8-sigma safe
#define WT_LD   260            // Wt stride: start-bank 4(o+q)%32 == canonical float4 pattern
#define SLOTS   8              // BN accumulator slots (atomic contention split)

typedef unsigned int u32;

__device__ __forceinline__ float lrelu(float x) {
    return fmaxf(x, LEAKY * x);   // slope in (0,1): monotone increasing
}

// D1: bitmap zero + Sacc/Qacc zero + hp = h@W, f1 = hp@a1, f2 = hp@a2.
// 256 blocks (1/CU), 4 waves x 8 rows. W transposed in LDS; h rows via the
// scalar pipe (wave-uniform base -> s_load), no LDS h staging.
__global__ __launch_bounds__(256) void k_pre(
    const float* __restrict__ h, const float* __restrict__ W, const float* __restrict__ a,
    float* __restrict__ hp, float* __restrict__ f1, float* __restrict__ f2,
    u32* __restrict__ bm, float* __restrict__ Sacc)
{
    __shared__ float Wt[F_OUT * WT_LD];   // 66,560 B (transposed, padded)
    const int tid = threadIdx.x;
    const int w = tid >> 6, lane = tid & 63;
    const int b = blockIdx.x;

    // Zero this block's 32KB bitmap slice (float4 stores)
    {
        const float4 z = {0.f, 0.f, 0.f, 0.f};
        float4* dst = reinterpret_cast<float4*>(bm + (size_t)b * 8192);
#pragma unroll
        for (int p = 0; p < 8; ++p) dst[tid + p * 256] = z;
        if (b == 0 && tid < 256)   // Sacc+Qacc = 4 KB contiguous
            reinterpret_cast<float4*>(Sacc)[tid] = z;
    }

    // Transpose W[k][o] -> Wt[o][k], 8x8 tiles: write banks ~2-way (free)
#pragma unroll
    for (int t = 0; t < 64; ++t) {
        const int T = t * 4 + w;
        const int o = (T & 7) * 8 + (lane & 7);
        const int k = (T >> 3) * 8 + (lane >> 3);
        Wt[o * WT_LD + k] = W[k * F_OUT + o];
    }
    __syncthreads();

    const int row0 = b * 32;
    const int wu = __builtin_amdgcn_readfirstlane(w);   // provably wave-uniform
    const float* hb = h + (size_t)(row0 + wu * 8) * F_IN;
    const int o = lane;

    float acc[8] = {0.f, 0.f, 0.f, 0.f, 0.f, 0.f, 0.f, 0.f};
    for (int q = 0; q < 64; ++q) {
        const float4 wv = *reinterpret_cast<const float4*>(&Wt[o * WT_LD + 4 * q]);
#pragma unroll
        for (int r = 0; r < 8; ++r) {
            const float4 hq = *reinterpret_cast<const float4*>(&hb[r * F_IN + 4 * q]);
            acc[r] += wv.x * hq.x + wv.y * hq.y + wv.z * hq.z + wv.w * hq.w;
        }
    }

    const float a1 = a[o], a2 = a[F_OUT + o];
#pragma unroll
    for (int r = 0; r < 8; ++r) {
        const int row = row0 + wu * 8 + r;
        hp[row * F_OUT + o] = acc[r];
        float p1 = acc[r] * a1;
        float p2 = acc[r] * a2;
#pragma unroll
        for (int off = 32; off; off >>= 1) {
            p1 += __shfl_xor(p1, off, 64);
            p2 += __shfl_xor(p2, off, 64);
        }
        if (o == 0) { f1[row] = p1; f2[row] = p2; }
    }
}

// D2 (cooperative, 1024 blocks x 256): edge scatter -> grid.sync ->
// per-row softmax+gather (2 rows/wave, attention values kept in registers)
// + BN partials -> grid.sync -> BN finalize+apply (from registers) + alpha.
__global__ __launch_bounds__(256, 4) void k_main(
    const int* __restrict__ ei, const float* __restrict__ hp,
    const float* __restrict__ f1g, const float* __restrict__ f2g,
    const float* __restrict__ gamma, const float* __restrict__ beta,
    const float* __restrict__ bias,
    u32* __restrict__ bm, float* __restrict__ Mg, float* __restrict__ Dg,
    float* __restrict__ Sacc, float* __restrict__ Qacc, float* __restrict__ out)
{
    __shared__ int   nbr[4][MAXDEG];            // 4 KB
    __shared__ float fv [4][MAXDEG];            // 4 KB
    __shared__ float bnS[4][F_OUT], bnQ[4][F_OUT];  // 2 KB
    __shared__ float fin[4][F_OUT];             // 1 KB: mean/rstd/gamma/beta+bias
    cg::grid_group grid = cg::this_grid();
    const int tid = threadIdx.x;
    const int w = tid >> 6, lane = tid & 63;
    const int b = blockIdx.x;

    // ---- Phase A: edge scatter into bitmap (r,c kept for alpha phase) ----
    const int e = b * 256 + tid;
    const int er = ei[e];
    const int ec = ei[N_EDGES + e];
    atomicOr(&bm[(size_t)er * WPR + (ec >> 5)], 1u << (ec & 31));
    grid.sync();

    // ---- Phase B: rows b*8 .. b*8+7, 2 per wave ----
    float vsave[2];
    float myS = 0.f, myQ = 0.f;
    int* nb = nbr[w];
    float* fvv = fv[w];
#pragma unroll
    for (int rr = 0; rr < 2; ++rr) {
        const int row = b * 8 + w * 2 + rr;
        const uint4 bw = reinterpret_cast<const uint4*>(bm + (size_t)row * WPR)[lane];
        const int tot = __popc(bw.x) + __popc(bw.y) + __popc(bw.z) + __popc(bw.w);
        int pref = tot;                      // inclusive lane prefix
#pragma unroll
        for (int off = 1; off < 64; off <<= 1) {
            const int t2 = __shfl_up(pref, off, 64);
            if (lane >= off) pref += t2;
        }
        const int deg0 = __shfl(pref, 63, 64);
        int pos = pref - tot;                // exclusive
        float mymax = -1e30f;
        const u32 words[4] = {bw.x, bw.y, bw.z, bw.w};
#pragma unroll
        for (int i = 0; i < 4; ++i) {
            u32 bits = words[i];
            const int jbase = (lane * 4 + i) * 32;
            while (bits) {
                const int bit = __ffs(bits) - 1;
                bits &= bits - 1;
                const int j = jbase + bit;
                const float v = f2g[j];      // 32 KB table: L1/L2-resident
                mymax = fmaxf(mymax, v);
                if (pos < MAXDEG) { nb[pos] = j; fvv[pos] = v; }
                ++pos;
            }
        }
#pragma unroll
        for (int off = 32; off; off >>= 1)
            mymax = fmaxf(mymax, __shfl_xor(mymax, off, 64));

        const int dg = min(deg0, MAXDEG);
        const float f1i = f1g[row];
        float M = lrelu(f1i + mymax);
        float den0 = 0.f, den1 = 0.f, ac0 = 0.f, ac1 = 0.f;
        int n = 0;
        for (; n + 2 <= dg; n += 2) {
            const int j0 = nb[n], j1 = nb[n + 1];
            const float w0 = __expf(lrelu(f1i + fvv[n]) - M);
            const float w1 = __expf(lrelu(f1i + fvv[n + 1]) - M);
            den0 += w0;  den1 += w1;
            ac0 += w0 * hp[j0 * F_OUT + lane];
            ac1 += w1 * hp[j1 * F_OUT + lane];
        }
        if (n < dg) {
            const float w0 = __expf(lrelu(f1i + fvv[n]) - M);
            den0 += w0;
            ac0 += w0 * hp[nb[n] * F_OUT + lane];
        }
        float den = den0 + den1;
        float v = (ac0 + ac1) / den;
        if (dg == 0) { den = 1.f; M = 0.f; v = 0.f; }   // degenerate guard (P ~ e^-32)
        vsave[rr] = v;
        myS += v; myQ += v * v;
        if (lane == 0) { Mg[row] = M; Dg[row] = den; }
    }
    bnS[w][lane] = myS;
    bnQ[w][lane] = myQ;
    __syncthreads();
    if (w == 0) {
        const float s = bnS[0][lane] + bnS[1][lane] + bnS[2][lane] + bnS[3][lane];
        const float q = bnQ[0][lane] + bnQ[1][lane] + bnQ[2][lane] + bnQ[3][lane];
        const int slot = b & (SLOTS - 1);
        atomicAdd(&Sacc[slot * F_OUT + lane], s);
        atomicAdd(&Qacc[slot * F_OUT + lane], q);
    }
    grid.sync();

    // ---- Phase C: BN finalize + apply (register-resident rows) + alpha ----
    if (tid < F_OUT) {
        float s = 0.f, q = 0.f;
#pragma unroll
        for (int k = 0; k < SLOTS; ++k) {
            s += Sacc[k * F_OUT + tid];
            q += Qacc[k * F_OUT + tid];
        }
        const float mean = s * (1.f / N_NODES);
        const float var = q * (1.f / N_NODES) - mean * mean;
        fin[0][tid] = mean;
        fin[1][tid] = rsqrtf(var + BN_EPSF);
        fin[2][tid] = gamma[tid];
        fin[3][tid] = beta[tid] + bias[tid];
    }
    __syncthreads();
#pragma unroll
    for (int rr = 0; rr < 2; ++rr) {
        const int row = b * 8 + w * 2 + rr;
        out[row * F_OUT + lane] =
            (vsave[rr] - fin[0][lane]) * fin[1][lane] * fin[2][lane] + fin[3][lane];
    }
    out[N_NODES * F_OUT + e] = __expf(lrelu(f1g[er] + f2g[ec]) - Mg[er]) / Dg[er];
}

extern "C" void kernel_launch(void* const* d_in, const int* in_sizes, int n_in,
                              void* d_out, int out_size, void* d_ws, size_t ws_size,
                              hipStream_t stream) {
    const float* h     = (const float*)d_in[0];
    const int*   ei    = (const int*)  d_in[1];
    const float* W     = (const float*)d_in[2];
    const float* a     = (const float*)d_in[3];
    const float* bias  = (const float*)d_in[4];
    const float* gamma = (const float*)d_in[5];
    const float* beta  = (const float*)d_in[6];
    float* out = (float*)d_out;

    char* ws = (char*)d_ws;
    float* hp    = (float*)(ws + 0);          // 2 MB
    float* f1    = (float*)(ws + 2097152);    // 32 KB
    float* f2    = (float*)(ws + 2129920);    // 32 KB
    float* Mg    = (float*)(ws + 2162688);    // 32 KB
    float* Dg    = (float*)(ws + 2195456);    // 32 KB
    float* Sacc  = (float*)(ws + 2228224);    // 2 KB (8 slots x 64)  } zeroed as one
    float* Qacc  = (float*)(ws + 2230272);    // 2 KB                 } 4 KB range
    u32*   bm    = (u32*)  (ws + 2232320);    // 8 MB
    if (ws_size < (size_t)2232320 + (size_t)N_NODES * WPR * 4) return;

    k_pre<<<256, 256, 0, stream>>>(h, W, a, hp, f1, f2, bm, Sacc);

    void* args[] = {(void*)&ei, (void*)&hp, (void*)&f1, (void*)&f2,
                    (void*)&gamma, (void*)&beta, (void*)&bias,
                    (void*)&bm, (void*)&Mg, (void*)&Dg,
                    (void*)&Sacc, (void*)&Qacc, (void*)&out};
    hipLaunchCooperativeKernel((void*)k_main, dim3(1024), dim3(256), args, 0, stream);
}

// Round 8
// 116.169 us; speedup vs baseline: 2.7762x; 2.7762x over previous
//
#include <hip/hip_runtime.h>
#include <stdint.h>

// Problem constants (fixed by reference setup_inputs)
#define N_NODES 8192
#define F_IN    256
#define F_OUT   64
#define N_EDGES 262144
#define LEAKY   0.2f
#define BN_EPSF 1e-5f
#define MAXDEG  256            // Poisson(32): max row degree ~66; 256 is 8-sigma safe
#define WT_LD   260            // Wt stride: start-bank 4(o+q)%32 == canonical float4 pattern
#define SLOTS   8              // BN accumulator slots (atomic contention split)

typedef unsigned int u32;
typedef unsigned long long u64;

__device__ __forceinline__ float lrelu(float x) {
    return fmaxf(x, LEAKY * x);   // slope in (0,1): monotone increasing
}

// D2: blocks [0,256): hp = h@W, f1 = hp@a1, f2 = hp@a2 (W transposed in LDS,
// h via scalar pipe). blocks [256,1280): scatter edges into per-row packed
// lists: elist[r][pos] = (e<<13)|c  (13 bits col, 18 bits edge id).
// The two halves are data-independent; fusing them saves one graph node.
__global__ __launch_bounds__(256) void k_gs(
    const float* __restrict__ h, const float* __restrict__ W, const float* __restrict__ a,
    const int* __restrict__ ei,
    float* __restrict__ hp, float* __restrict__ f1, float* __restrict__ f2,
    u32* __restrict__ cnt, u32* __restrict__ elist)
{
    __shared__ float Wt[F_OUT * WT_LD];   // 66,560 B (transposed, padded)
    const int tid = threadIdx.x;

    if (blockIdx.x >= 256) {              // ---- scatter half ----
        const int e = (blockIdx.x - 256) * 256 + tid;
        const int r = ei[e];
        const int c = ei[N_EDGES + e];
        const int pos = atomicAdd(&cnt[r], 1u);
        if (pos < MAXDEG)
            elist[r * MAXDEG + pos] = ((u32)e << 13) | (u32)c;
        return;
    }

    // ---- GEMM half ----
    const int w = tid >> 6, lane = tid & 63;
    const int b = blockIdx.x;

    // Transpose W[k][o] -> Wt[o][k], 8x8 tiles: write banks ~2-way (free)
#pragma unroll
    for (int t = 0; t < 64; ++t) {
        const int T = t * 4 + w;
        const int o = (T & 7) * 8 + (lane & 7);
        const int k = (T >> 3) * 8 + (lane >> 3);
        Wt[o * WT_LD + k] = W[k * F_OUT + o];
    }
    __syncthreads();

    const int row0 = b * 32;
    const int wu = __builtin_amdgcn_readfirstlane(w);   // provably wave-uniform
    const float* hb = h + (size_t)(row0 + wu * 8) * F_IN;
    const int o = lane;

    float acc[8] = {0.f, 0.f, 0.f, 0.f, 0.f, 0.f, 0.f, 0.f};
    for (int q = 0; q < 64; ++q) {
        const float4 wv = *reinterpret_cast<const float4*>(&Wt[o * WT_LD + 4 * q]);
#pragma unroll
        for (int r = 0; r < 8; ++r) {
            const float4 hq = *reinterpret_cast<const float4*>(&hb[r * F_IN + 4 * q]);
            acc[r] += wv.x * hq.x + wv.y * hq.y + wv.z * hq.z + wv.w * hq.w;
        }
    }

    const float a1 = a[o], a2 = a[F_OUT + o];
#pragma unroll
    for (int r = 0; r < 8; ++r) {
        const int row = row0 + wu * 8 + r;
        hp[row * F_OUT + o] = acc[r];
        float p1 = acc[r] * a1;
        float p2 = acc[r] * a2;
#pragma unroll
        for (int off = 32; off; off >>= 1) {
            p1 += __shfl_xor(p1, off, 64);
            p2 += __shfl_xor(p2, off, 64);
        }
        if (o == 0) { f1[row] = p1; f2[row] = p2; }
    }
}

// D3: 1 wave per row (2048 blocks x 4 waves). Read the row's packed edge
// list (~32 entries), dedup via per-wave 1KB LDS bitmap, kept entries stay
// in registers; softmax weights + 256B hp gathers via shfl broadcast.
// Fused: alpha scatter (every original edge) + BN partial sums.
// Raw attention output v goes to out[row*64+lane] (BN applied in-place by D4).
__global__ __launch_bounds__(256) void k_attn(
    const u32* __restrict__ cnt, const u32* __restrict__ elist,
    const float* __restrict__ hp, const float* __restrict__ f1g,
    const float* __restrict__ f2g,
    float* __restrict__ Sacc, float* __restrict__ Qacc, float* __restrict__ out)
{
    __shared__ u32   dbm[4][256];                   // 4 x 1KB dedup bitmaps
    __shared__ float bnS[4][F_OUT], bnQ[4][F_OUT];  // 2 KB
    const int tid = threadIdx.x;
    const int w = tid >> 6, lane = tid & 63;
    const int row = blockIdx.x * 4 + w;

    const int dg = min((int)cnt[row], MAXDEG);
    const float f1i = f1g[row];
    const int nch = (dg + 63) >> 6;                 // chunks of 64 entries (~1)

    // zero my wave's dedup bitmap (same-wave DS ordering: no barrier needed)
    {
        const uint4 z = {0u, 0u, 0u, 0u};
        reinterpret_cast<uint4*>(dbm[w])[lane] = z;
    }

    int   cc[4]; u32 ee[4]; float vv[4];
    float mymax = -1e30f;
#pragma unroll 4
    for (int k = 0; k < nch; ++k) {
        const int idx = k * 64 + lane;
        const u32 pv = (idx < dg) ? elist[row * MAXDEG + idx] : 0u;
        cc[k] = pv & 8191u;
        ee[k] = pv >> 13;
        vv[k] = (idx < dg) ? f2g[cc[k]] : -1e30f;   // 32KB table: L1-resident
        mymax = fmaxf(mymax, vv[k]);
    }
#pragma unroll
    for (int off = 32; off; off >>= 1)
        mymax = fmaxf(mymax, __shfl_xor(mymax, off, 64));
    const float M = lrelu(f1i + mymax);

    // dedup (test-and-set) + weights + denominator
    float wgt[4]; u64 keep[4];
    float den = 0.f;
#pragma unroll 4
    for (int k = 0; k < nch; ++k) {
        const int idx = k * 64 + lane;
        bool kp = false;
        wgt[k] = 0.f;
        if (idx < dg) {
            const u32 bit = 1u << (cc[k] & 31);
            const u32 old = atomicOr(&dbm[w][cc[k] >> 5], bit);
            kp = !(old & bit);
            wgt[k] = __expf(lrelu(f1i + vv[k]) - M);
        }
        keep[k] = __ballot(kp);
        den += kp ? wgt[k] : 0.f;
    }
#pragma unroll
    for (int off = 32; off; off >>= 1)
        den += __shfl_xor(den, off, 64);

    // gather: iterate kept entries via wave-uniform ballot mask
    float acc = 0.f;
#pragma unroll 4
    for (int k = 0; k < nch; ++k) {
        u64 m = keep[k];
        while (m) {
            const int n = __ffsll((unsigned long long)m) - 1;
            m &= m - 1;
            const int j = __shfl(cc[k], n, 64);
            const float wn = __shfl(wgt[k], n, 64);
            acc += wn * hp[j * F_OUT + lane];       // 256B coalesced gather
        }
    }
    float v = (dg == 0) ? 0.f : acc / den;          // degenerate guard (P ~ e^-32)
    out[row * F_OUT + lane] = v;                    // raw; BN applied in-place by D4

    // alpha for EVERY original edge (duplicates get the identical value, as in ref)
#pragma unroll 4
    for (int k = 0; k < nch; ++k) {
        const int idx = k * 64 + lane;
        if (idx < dg)
            out[N_NODES * F_OUT + ee[k]] = wgt[k] / den;
    }

    // fused BN partials: block-level feature sums, one atomic set per block
    bnS[w][lane] = v;
    bnQ[w][lane] = v * v;
    __syncthreads();
    if (w == 0) {
        const float s = bnS[0][lane] + bnS[1][lane] + bnS[2][lane] + bnS[3][lane];
        const float q = bnQ[0][lane] + bnQ[1][lane] + bnQ[2][lane] + bnQ[3][lane];
        const int slot = blockIdx.x & (SLOTS - 1);
        atomicAdd(&Sacc[slot * F_OUT + lane], s);
        atomicAdd(&Qacc[slot * F_OUT + lane], q);
    }
}

// D4: BN finalize + in-place apply on out[0 .. N*F), float4.
__global__ __launch_bounds__(256) void k_bn(
    const float* __restrict__ Sacc, const float* __restrict__ Qacc,
    const float* __restrict__ gamma, const float* __restrict__ beta,
    const float* __restrict__ bias, float* __restrict__ out)
{
    __shared__ float sm[F_OUT], sr[F_OUT], sg[F_OUT], sb[F_OUT];
    const int tid = threadIdx.x;
    if (tid < F_OUT) {
        float s = 0.f, q = 0.f;
#pragma unroll
        for (int k = 0; k < SLOTS; ++k) {
            s += Sacc[k * F_OUT + tid];
            q += Qacc[k * F_OUT + tid];
        }
        const float mean = s * (1.f / N_NODES);
        const float var = q * (1.f / N_NODES) - mean * mean;
        sm[tid] = mean;
        sr[tid] = rsqrtf(var + BN_EPSF);
        sg[tid] = gamma[tid];
        sb[tid] = beta[tid] + bias[tid];
    }
    __syncthreads();
    const int gid = blockIdx.x * 256 + tid;          // float4 index
    const float4 ov = reinterpret_cast<const float4*>(out)[gid];
    const int o0 = (gid & 15) * 4;
    float4 res;
    res.x = (ov.x - sm[o0 + 0]) * sr[o0 + 0] * sg[o0 + 0] + sb[o0 + 0];
    res.y = (ov.y - sm[o0 + 1]) * sr[o0 + 1] * sg[o0 + 1] + sb[o0 + 1];
    res.z = (ov.z - sm[o0 + 2]) * sr[o0 + 2] * sg[o0 + 2] + sb[o0 + 2];
    res.w = (ov.w - sm[o0 + 3]) * sr[o0 + 3] * sg[o0 + 3] + sb[o0 + 3];
    reinterpret_cast<float4*>(out)[gid] = res;
}

extern "C" void kernel_launch(void* const* d_in, const int* in_sizes, int n_in,
                              void* d_out, int out_size, void* d_ws, size_t ws_size,
                              hipStream_t stream) {
    const float* h     = (const float*)d_in[0];
    const int*   ei    = (const int*)  d_in[1];
    const float* W     = (const float*)d_in[2];
    const float* a     = (const float*)d_in[3];
    const float* bias  = (const float*)d_in[4];
    const float* gamma = (const float*)d_in[5];
    const float* beta  = (const float*)d_in[6];
    float* out = (float*)d_out;

    char* ws = (char*)d_ws;
    u32*   cnt   = (u32*)  (ws + 0);          // 32 KB  } zeroed by one
    float* Sacc  = (float*)(ws + 32768);      // 2 KB   } 36,864-byte
    float* Qacc  = (float*)(ws + 34816);      // 2 KB   } memset
    float* hp    = (float*)(ws + 36864);      // 2 MB
    float* f1    = (float*)(ws + 2134016);    // 32 KB
    float* f2    = (float*)(ws + 2166784);    // 32 KB
    u32*   elist = (u32*)  (ws + 2199552);    // 8 MB packed (e<<13)|c
    if (ws_size < (size_t)2199552 + (size_t)N_NODES * MAXDEG * 4) return;

    hipMemsetAsync(ws, 0, 36864, stream);                               // D1
    k_gs  <<<1280, 256, 0, stream>>>(h, W, a, ei, hp, f1, f2, cnt, elist); // D2
    k_attn<<<N_NODES / 4, 256, 0, stream>>>(cnt, elist, hp, f1, f2,
                                            Sacc, Qacc, out);           // D3
    k_bn  <<<(N_NODES * F_OUT) / 1024, 256, 0, stream>>>(Sacc, Qacc, gamma,
                                                         beta, bias, out); // D4
}